// Round 2
// baseline (96.801 us; speedup 1.0000x reference)
//
#include <hip/hip_runtime.h>
#include <hip/hip_bf16.h>

#define BATCH 16384
#define FDIM  256
#define EDIM  128
#define KN    32

// ws layout:
//   [0, CAT_BYTES)            : cat[16384][512] bf16, row stride 1024 B,
//                               within-row granules XOR-swizzled by (row&7)<<4
//   [CAT_BYTES, +WB_BYTES)    : Bt bf16, 4 kt-chunks of [128 c][256 B],
//                               within-c-row granules XOR'd by (c&7)<<4
#define CAT_BYTES ((size_t)BATCH * 1024)
#define WB_BYTES  ((size_t)512 * EDIM * 2)

typedef __bf16 bf16x8 __attribute__((ext_vector_type(8)));
typedef float  f32x4  __attribute__((ext_vector_type(4)));

__device__ __forceinline__ unsigned short f2bf(float x) {
    return __builtin_bit_cast(unsigned short, (__bf16)x);
}

// ---------------- kernel C: W[512][128] f32 -> swizzled Bt bf16 in ws ----------------
__global__ void conv_w(const float* __restrict__ weight, char* __restrict__ wb)
{
    const int t  = blockIdx.x * 256 + threadIdx.x;   // 8192 threads, one granule each
    const int c  = t & 127;
    const int g  = (t >> 7) & 15;
    const int kt = t >> 11;
    union { unsigned short u[8]; uint4 v; } p;
    #pragma unroll
    for (int j = 0; j < 8; ++j)
        p.u[j] = f2bf(weight[(size_t)(kt * 128 + g * 8 + j) * EDIM + c]);
    *(uint4*)(wb + (size_t)kt * 32768 + c * 256 + ((g * 16) ^ ((c & 7) << 4))) = p.v;
}

// ---------------- kernel A: gather + mean -> swizzled cat bf16 in ws ----------------
// one wave per batch row; lane l covers feature float4 #l (64 lanes x 16 B = full row)
__global__ __launch_bounds__(256, 4)
void gather_agg(const int* __restrict__ nodes, const int* __restrict__ neigh,
                const float* __restrict__ feat, char* __restrict__ cat)
{
    const int lane = threadIdx.x & 63;
    const int row  = __builtin_amdgcn_readfirstlane(blockIdx.x * 4 + (threadIdx.x >> 6));
    const int s    = (row & 7) << 4;

    const int nid = __builtin_amdgcn_readfirstlane(nodes[row]);
    float4 sf = ((const float4*)(feat + (size_t)nid * FDIM))[lane];

    const int* nb = neigh + (size_t)row * KN;
    float ax = 0.f, ay = 0.f, az = 0.f, aw = 0.f;
    #pragma unroll
    for (int k = 0; k < KN; k += 8) {
        int id[8];
        #pragma unroll
        for (int j = 0; j < 8; ++j)
            id[j] = __builtin_amdgcn_readfirstlane(nb[k + j]);
        float4 v[8];
        #pragma unroll
        for (int j = 0; j < 8; ++j)
            v[j] = ((const float4*)(feat + (size_t)id[j] * FDIM))[lane];
        #pragma unroll
        for (int j = 0; j < 8; ++j) {
            ax += v[j].x; ay += v[j].y; az += v[j].z; aw += v[j].w;
        }
    }

    char* rowp = cat + (size_t)row * 1024;
    {
        union { unsigned short u[4]; uint2 v; } p;
        p.u[0] = f2bf(sf.x); p.u[1] = f2bf(sf.y);
        p.u[2] = f2bf(sf.z); p.u[3] = f2bf(sf.w);
        *(uint2*)(rowp + ((lane * 8) ^ s)) = p.v;
    }
    {
        const float inv = 1.0f / 32.0f;
        union { unsigned short u[4]; uint2 v; } p;
        p.u[0] = f2bf(ax * inv); p.u[1] = f2bf(ay * inv);
        p.u[2] = f2bf(az * inv); p.u[3] = f2bf(aw * inv);
        *(uint2*)(rowp + ((512 + lane * 8) ^ s)) = p.v;
    }
}

// ---------------- kernel B: out = relu(cat @ W), bf16 MFMA ----------------
// 256 blocks x 256 thr; block = 64 rows x 128 cols; wave w = rows w*16..+16, all cols
__global__ __launch_bounds__(256, 2)
void gemm_out(const char* __restrict__ cat, const char* __restrict__ wb,
              float* __restrict__ out)
{
    __shared__ __align__(16) char lds_a[64 * 256];    // 16 KB: [64 rows][256 B] per kt
    __shared__ __align__(16) char lds_b[128 * 256];   // 32 KB: [128 c][256 B] per kt

    const int t    = threadIdx.x;
    const int lane = t & 63;
    const int w    = t >> 6;
    const int m0   = blockIdx.x * 64;
    const int r0   = w * 16;
    const int q    = lane >> 4;
    const int p    = lane & 15;
    const int ps   = (p & 7) << 4;

    f32x4 acc[8];
    #pragma unroll
    for (int n = 0; n < 8; ++n) acc[n] = (f32x4){0.f, 0.f, 0.f, 0.f};

    for (int kt = 0; kt < 4; ++kt) {
        // stage A chunk: 64 rows x 256 B (linear copy per row; swizzle pre-applied in ws)
        #pragma unroll
        for (int i = 0; i < 4; ++i) {
            const int g   = i * 256 + t;          // granule 0..1023
            const int row = g >> 4;
            const int x   = (g & 15) * 16;
            __builtin_amdgcn_global_load_lds(
                (const void*)(cat + (size_t)(m0 + row) * 1024 + kt * 256 + x),
                (void*)(lds_a + g * 16), 16, 0, 0);
        }
        // stage B chunk: straight 32 KB linear copy
        #pragma unroll
        for (int i = 0; i < 8; ++i) {
            const int g = i * 256 + t;
            __builtin_amdgcn_global_load_lds(
                (const void*)(wb + (size_t)kt * 32768 + g * 16),
                (void*)(lds_b + g * 16), 16, 0, 0);
        }
        __syncthreads();

        #pragma unroll
        for (int kk = 0; kk < 4; ++kk) {
            const int xo = (kk * 64 + q * 16);
            bf16x8 a = *(const bf16x8*)(lds_a + (r0 + p) * 256 + (xo ^ ps));
            #pragma unroll
            for (int n = 0; n < 8; ++n) {
                bf16x8 b = *(const bf16x8*)(lds_b + (n * 16 + p) * 256 + (xo ^ ps));
                acc[n] = __builtin_amdgcn_mfma_f32_16x16x32_bf16(a, b, acc[n], 0, 0, 0);
            }
        }
        __syncthreads();
    }

    #pragma unroll
    for (int n = 0; n < 8; ++n) {
        #pragma unroll
        for (int j = 0; j < 4; ++j) {
            const float v = acc[n][j];
            out[(size_t)(m0 + r0 + q * 4 + j) * EDIM + n * 16 + p] = v > 0.f ? v : 0.f;
        }
    }
}

// ---------------- fallback: round-1 fused kernel (used only if ws too small) ----------------
#define BM 32
__global__ __launch_bounds__(256, 2)
void sage_fused(const int* __restrict__ nodes,
                const int* __restrict__ neigh,
                const float* __restrict__ feat,
                const float* __restrict__ weight,
                float* __restrict__ out)
{
    __shared__ __align__(16) char cat_raw[BM * 1024];
    __shared__ __align__(16) char bt_raw[128 * 256];

    const int t    = threadIdx.x;
    const int lane = t & 63;
    const int w    = t >> 6;
    const int b0   = blockIdx.x * BM;

    int* ls_nei   = (int*)bt_raw;
    int* ls_nodes = (int*)(bt_raw + 4096);
    ((int4*)ls_nei)[t] = ((const int4*)(neigh + (size_t)b0 * KN))[t];
    if (t < BM) ls_nodes[t] = nodes[b0 + t];
    __syncthreads();

    for (int rr = 0; rr < 8; ++rr) {
        const int r   = w * 8 + rr;
        const int swz = (r & 7) << 4;
        const int nid = ls_nodes[r];
        float4 s = ((const float4*)(feat + (size_t)nid * FDIM))[lane];
        {
            union { unsigned short u[4]; uint2 v; } p;
            p.u[0] = f2bf(s.x); p.u[1] = f2bf(s.y);
            p.u[2] = f2bf(s.z); p.u[3] = f2bf(s.w);
            *(uint2*)(cat_raw + ((r * 1024 + lane * 8) ^ swz)) = p.v;
        }
        float ax = 0.f, ay = 0.f, az = 0.f, aw = 0.f;
        #pragma unroll
        for (int k = 0; k < KN; k += 4) {
            const int i0 = ls_nei[r * KN + k + 0];
            const int i1 = ls_nei[r * KN + k + 1];
            const int i2 = ls_nei[r * KN + k + 2];
            const int i3 = ls_nei[r * KN + k + 3];
            float4 v0 = ((const float4*)(feat + (size_t)i0 * FDIM))[lane];
            float4 v1 = ((const float4*)(feat + (size_t)i1 * FDIM))[lane];
            float4 v2 = ((const float4*)(feat + (size_t)i2 * FDIM))[lane];
            float4 v3 = ((const float4*)(feat + (size_t)i3 * FDIM))[lane];
            ax += v0.x + v1.x + v2.x + v3.x;
            ay += v0.y + v1.y + v2.y + v3.y;
            az += v0.z + v1.z + v2.z + v3.z;
            aw += v0.w + v1.w + v2.w + v3.w;
        }
        const float inv = 1.0f / 32.0f;
        union { unsigned short u[4]; uint2 v; } p;
        p.u[0] = f2bf(ax * inv); p.u[1] = f2bf(ay * inv);
        p.u[2] = f2bf(az * inv); p.u[3] = f2bf(aw * inv);
        *(uint2*)(cat_raw + ((r * 1024 + 512 + lane * 8) ^ swz)) = p.v;
    }
    __syncthreads();

    const int wr = w >> 1, wc = w & 1;
    const int r0 = wr * 16;
    const int c0 = wc * 64;
    const int q  = lane >> 4;
    const int p  = lane & 15;

    f32x4 acc[4] = {{0,0,0,0},{0,0,0,0},{0,0,0,0},{0,0,0,0}};

    for (int kt = 0; kt < 4; ++kt) {
        {
            const int c    = t & 127;
            const int kh   = (t >> 7) * 64;
            const int cswz = (c & 7) << 4;
            #pragma unroll
            for (int k8 = 0; k8 < 8; ++k8) {
                const int kl = kh + k8 * 8;
                union { unsigned short u[8]; uint4 v; } pk;
                #pragma unroll
                for (int j = 0; j < 8; ++j)
                    pk.u[j] = f2bf(weight[(size_t)(kt * 128 + kl + j) * EDIM + c]);
                *(uint4*)(bt_raw + ((c * 256 + kl * 2) ^ cswz)) = pk.v;
            }
        }
        __syncthreads();
        #pragma unroll
        for (int kk = 0; kk < 4; ++kk) {
            const int row = r0 + p;
            const int kb  = (kt * 128 + kk * 32 + q * 8) * 2;
            bf16x8 a = *(const bf16x8*)(cat_raw + ((row * 1024 + kb) ^ ((row & 7) << 4)));
            const int klb = (kk * 32 + q * 8) * 2;
            #pragma unroll
            for (int n = 0; n < 4; ++n) {
                const int c = c0 + n * 16 + p;
                bf16x8 b = *(const bf16x8*)(bt_raw + ((c * 256 + klb) ^ ((c & 7) << 4)));
                acc[n] = __builtin_amdgcn_mfma_f32_16x16x32_bf16(a, b, acc[n], 0, 0, 0);
            }
        }
        __syncthreads();
    }

    #pragma unroll
    for (int n = 0; n < 4; ++n) {
        #pragma unroll
        for (int j = 0; j < 4; ++j) {
            const int row = r0 + q * 4 + j;
            const int col = c0 + n * 16 + p;
            float v = acc[n][j];
            out[(size_t)(b0 + row) * EDIM + col] = v > 0.f ? v : 0.f;
        }
    }
}

extern "C" void kernel_launch(void* const* d_in, const int* in_sizes, int n_in,
                              void* d_out, int out_size, void* d_ws, size_t ws_size,
                              hipStream_t stream) {
    const int*   nodes  = (const int*)d_in[0];
    const int*   neigh  = (const int*)d_in[1];
    const float* feat   = (const float*)d_in[2];
    const float* weight = (const float*)d_in[3];
    float*       out    = (float*)d_out;

    if (ws_size >= CAT_BYTES + WB_BYTES) {
        char* cat = (char*)d_ws;
        char* wb  = (char*)d_ws + CAT_BYTES;
        conv_w<<<32, 256, 0, stream>>>(weight, wb);
        gather_agg<<<BATCH / 4, 256, 0, stream>>>(nodes, neigh, feat, cat);
        gemm_out<<<BATCH / 64, 256, 0, stream>>>(cat, wb, out);
    } else {
        sage_fused<<<BATCH / BM, 256, 0, stream>>>(nodes, neigh, feat, weight, out);
    }
}

// Round 3
// 60.573 us; speedup vs baseline: 1.5981x; 1.5981x over previous
//
#include <hip/hip_runtime.h>
#include <hip/hip_bf16.h>

#define BATCH  16384
#define FDIM   256
#define EDIM   128
#define KN     32
#define NNODES 100000

typedef __bf16 bf16x8 __attribute__((ext_vector_type(8)));
typedef float  f32x4  __attribute__((ext_vector_type(4)));

__device__ __forceinline__ unsigned short f2bf(float x) {
    return __builtin_bit_cast(unsigned short, (__bf16)x);
}
__device__ __forceinline__ float bflo(unsigned v) {
    return __builtin_bit_cast(float, v << 16);
}
__device__ __forceinline__ float bfhi(unsigned v) {
    return __builtin_bit_cast(float, v & 0xffff0000u);
}

// ---------- new-path ws layout ----------
// S[NNODES][128] bf16  (self head:  F @ W[0:256,:])
// P[NNODES][128] bf16  (neigh head: F @ W[256:512,:])
// Wbt: combined B^T [j=256][k=256] bf16, 4 kt-chunks of [256 j][128 B],
//      16B granules XOR'd by (j&7)<<4 (pre-swizzled for linear global_load_lds)
#define SP_BYTES  ((size_t)NNODES * 256)
#define WBT_BYTES ((size_t)4 * 256 * 128)
#define NEW_WS    (2 * SP_BYTES + WBT_BYTES)

// ---------------- kernel: W[512][128] f32 -> swizzled Wbt bf16 ----------------
// Wc[k][j] = (j<128) ? W[k][j] : W[k+256][j-128],  k,j in [0,256)
__global__ void conv_w2(const float* __restrict__ weight, char* __restrict__ wbt)
{
    const int gid = blockIdx.x * 256 + threadIdx.x;   // 8192 granules
    const int kt  = gid >> 11;
    const int rem = gid & 2047;
    const int j   = rem >> 3;
    const int g   = rem & 7;
    union { unsigned short u[8]; uint4 v; } p;
    #pragma unroll
    for (int e = 0; e < 8; ++e) {
        const int k = kt * 64 + g * 8 + e;
        const float w = (j < 128) ? weight[(size_t)k * EDIM + j]
                                  : weight[(size_t)(k + 256) * EDIM + (j - 128)];
        p.u[e] = f2bf(w);
    }
    *(uint4*)(wbt + (size_t)kt * 32768 + j * 128 + ((g * 16) ^ ((j & 7) << 4))) = p.v;
}

// ---------------- kernel: proj  S|P = F @ Wc  (bf16 MFMA, f32 A converted in-kernel) ----
// block = 64 rows x 256 cols; 4 waves, wave w = rows w*16..+16, all 256 cols
__global__ __launch_bounds__(256, 2)
void proj(const float* __restrict__ feat, const char* __restrict__ wbt,
          char* __restrict__ Sb, char* __restrict__ Pb)
{
    __shared__ __align__(16) char lds_a[64 * 128];    // 8 KB: [64 r][128 B] per kt, swz
    __shared__ __align__(16) char lds_b[256 * 128];   // 32 KB: [256 j][128 B] per kt, swz

    const int t    = threadIdx.x;
    const int lane = t & 63;
    const int w    = t >> 6;
    const int m0   = blockIdx.x * 64;
    const int r0   = w * 16;
    const int q    = lane >> 4;
    const int p    = lane & 15;

    f32x4 acc[16];
    #pragma unroll
    for (int n = 0; n < 16; ++n) acc[n] = (f32x4){0.f, 0.f, 0.f, 0.f};

    const int r_st  = t >> 2;          // staging row 0..63
    const int q4    = t & 3;           // 16-elem quarter of the 64-k chunk
    const int gr    = (m0 + r_st < NNODES) ? (m0 + r_st) : (NNODES - 1);
    const int rswz  = (r_st & 7) << 4;

    for (int kt = 0; kt < 4; ++kt) {
        // stage A: rows m0..+64, k = kt*64..+64, f32 -> bf16, swizzled
        {
            const float4* src = (const float4*)(feat + (size_t)gr * FDIM + kt * 64 + q4 * 16);
            float4 f0 = src[0], f1 = src[1], f2 = src[2], f3 = src[3];
            union { unsigned short u[8]; uint4 v; } a0, a1;
            a0.u[0]=f2bf(f0.x); a0.u[1]=f2bf(f0.y); a0.u[2]=f2bf(f0.z); a0.u[3]=f2bf(f0.w);
            a0.u[4]=f2bf(f1.x); a0.u[5]=f2bf(f1.y); a0.u[6]=f2bf(f1.z); a0.u[7]=f2bf(f1.w);
            a1.u[0]=f2bf(f2.x); a1.u[1]=f2bf(f2.y); a1.u[2]=f2bf(f2.z); a1.u[3]=f2bf(f2.w);
            a1.u[4]=f2bf(f3.x); a1.u[5]=f2bf(f3.y); a1.u[6]=f2bf(f3.z); a1.u[7]=f2bf(f3.w);
            *(uint4*)(lds_a + r_st * 128 + ((q4 * 32     ) ^ rswz)) = a0.v;
            *(uint4*)(lds_a + r_st * 128 + ((q4 * 32 + 16) ^ rswz)) = a1.v;
        }
        // stage B: 32 KB linear copy (swizzle pre-applied in ws)
        #pragma unroll
        for (int i = 0; i < 8; ++i) {
            const int g = i * 256 + t;
            __builtin_amdgcn_global_load_lds(
                (const void*)(wbt + (size_t)kt * 32768 + g * 16),
                (void*)(lds_b + g * 16), 16, 0, 0);
        }
        __syncthreads();

        #pragma unroll
        for (int kk = 0; kk < 2; ++kk) {
            const int xo  = kk * 64 + q * 16;
            const int ar  = r0 + p;
            bf16x8 a = *(const bf16x8*)(lds_a + ar * 128 + (xo ^ ((ar & 7) << 4)));
            #pragma unroll
            for (int n = 0; n < 16; ++n) {
                const int br = n * 16 + p;
                bf16x8 b = *(const bf16x8*)(lds_b + br * 128 + (xo ^ ((br & 7) << 4)));
                acc[n] = __builtin_amdgcn_mfma_f32_16x16x32_bf16(a, b, acc[n], 0, 0, 0);
            }
        }
        __syncthreads();
    }

    // epilogue: bf16 store; cols 0..127 -> S, 128..255 -> P
    #pragma unroll
    for (int j = 0; j < 4; ++j) {
        const int row = m0 + r0 + q * 4 + j;
        if (row < NNODES) {
            #pragma unroll
            for (int n = 0; n < 16; ++n) {
                const int col = n * 16 + p;
                const unsigned short v = f2bf(acc[n][j]);
                if (col < 128)
                    *(unsigned short*)(Sb + (size_t)row * 256 + col * 2) = v;
                else
                    *(unsigned short*)(Pb + (size_t)row * 256 + (col - 128) * 2) = v;
            }
        }
    }
}

// ---------------- kernel: gather2  out[b] = relu(S[nodes[b]] + mean_k P[neigh]) ------
// one wave per batch row; lane covers 2 cols (uint = 2 bf16; float2 out)
__global__ __launch_bounds__(256, 4)
void gather2(const int* __restrict__ nodes, const int* __restrict__ neigh,
             const char* __restrict__ Sb, const char* __restrict__ Pb,
             float* __restrict__ out)
{
    const int lane = threadIdx.x & 63;
    const int b    = __builtin_amdgcn_readfirstlane(blockIdx.x * 4 + (threadIdx.x >> 6));

    const int nid = __builtin_amdgcn_readfirstlane(nodes[b]);
    const unsigned sv = *(const unsigned*)(Sb + (size_t)nid * 256 + lane * 4);

    const int* nb = neigh + (size_t)b * KN;
    float a0 = 0.f, a1 = 0.f;
    #pragma unroll
    for (int k = 0; k < KN; k += 8) {
        int id[8];
        #pragma unroll
        for (int j = 0; j < 8; ++j)
            id[j] = __builtin_amdgcn_readfirstlane(nb[k + j]);
        unsigned v[8];
        #pragma unroll
        for (int j = 0; j < 8; ++j)
            v[j] = *(const unsigned*)(Pb + (size_t)id[j] * 256 + lane * 4);
        #pragma unroll
        for (int j = 0; j < 8; ++j) {
            a0 += bflo(v[j]);
            a1 += bfhi(v[j]);
        }
    }

    const float inv = 1.0f / 32.0f;
    float o0 = bflo(sv) + a0 * inv;
    float o1 = bfhi(sv) + a1 * inv;
    o0 = o0 > 0.f ? o0 : 0.f;
    o1 = o1 > 0.f ? o1 : 0.f;
    ((float2*)out)[(size_t)b * 64 + lane] = make_float2(o0, o1);
}

// ================= fallback path (round-2): cat + gemm =================
#define CAT_BYTES ((size_t)BATCH * 1024)
#define WB_BYTES  ((size_t)512 * EDIM * 2)

__global__ void conv_w(const float* __restrict__ weight, char* __restrict__ wb)
{
    const int t  = blockIdx.x * 256 + threadIdx.x;
    const int c  = t & 127;
    const int g  = (t >> 7) & 15;
    const int kt = t >> 11;
    union { unsigned short u[8]; uint4 v; } p;
    #pragma unroll
    for (int j = 0; j < 8; ++j)
        p.u[j] = f2bf(weight[(size_t)(kt * 128 + g * 8 + j) * EDIM + c]);
    *(uint4*)(wb + (size_t)kt * 32768 + c * 256 + ((g * 16) ^ ((c & 7) << 4))) = p.v;
}

__global__ __launch_bounds__(256, 4)
void gather_agg(const int* __restrict__ nodes, const int* __restrict__ neigh,
                const float* __restrict__ feat, char* __restrict__ cat)
{
    const int lane = threadIdx.x & 63;
    const int row  = __builtin_amdgcn_readfirstlane(blockIdx.x * 4 + (threadIdx.x >> 6));
    const int s    = (row & 7) << 4;
    const int nid  = __builtin_amdgcn_readfirstlane(nodes[row]);
    float4 sf = ((const float4*)(feat + (size_t)nid * FDIM))[lane];
    const int* nb = neigh + (size_t)row * KN;
    float ax = 0.f, ay = 0.f, az = 0.f, aw = 0.f;
    #pragma unroll
    for (int k = 0; k < KN; k += 8) {
        int id[8];
        #pragma unroll
        for (int j = 0; j < 8; ++j) id[j] = __builtin_amdgcn_readfirstlane(nb[k + j]);
        float4 v[8];
        #pragma unroll
        for (int j = 0; j < 8; ++j) v[j] = ((const float4*)(feat + (size_t)id[j] * FDIM))[lane];
        #pragma unroll
        for (int j = 0; j < 8; ++j) { ax += v[j].x; ay += v[j].y; az += v[j].z; aw += v[j].w; }
    }
    char* rowp = cat + (size_t)row * 1024;
    {
        union { unsigned short u[4]; uint2 v; } p;
        p.u[0] = f2bf(sf.x); p.u[1] = f2bf(sf.y); p.u[2] = f2bf(sf.z); p.u[3] = f2bf(sf.w);
        *(uint2*)(rowp + ((lane * 8) ^ s)) = p.v;
    }
    {
        const float inv = 1.0f / 32.0f;
        union { unsigned short u[4]; uint2 v; } p;
        p.u[0] = f2bf(ax * inv); p.u[1] = f2bf(ay * inv);
        p.u[2] = f2bf(az * inv); p.u[3] = f2bf(aw * inv);
        *(uint2*)(rowp + ((512 + lane * 8) ^ s)) = p.v;
    }
}

__global__ __launch_bounds__(256, 2)
void gemm_out(const char* __restrict__ cat, const char* __restrict__ wb,
              float* __restrict__ out)
{
    __shared__ __align__(16) char lds_a[64 * 256];
    __shared__ __align__(16) char lds_b[128 * 256];
    const int t    = threadIdx.x;
    const int lane = t & 63;
    const int w    = t >> 6;
    const int m0   = blockIdx.x * 64;
    const int r0   = w * 16;
    const int q    = lane >> 4;
    const int p    = lane & 15;
    const int ps   = (p & 7) << 4;
    f32x4 acc[8];
    #pragma unroll
    for (int n = 0; n < 8; ++n) acc[n] = (f32x4){0.f, 0.f, 0.f, 0.f};
    for (int kt = 0; kt < 4; ++kt) {
        #pragma unroll
        for (int i = 0; i < 4; ++i) {
            const int g   = i * 256 + t;
            const int row = g >> 4;
            const int x   = (g & 15) * 16;
            __builtin_amdgcn_global_load_lds(
                (const void*)(cat + (size_t)(m0 + row) * 1024 + kt * 256 + x),
                (void*)(lds_a + g * 16), 16, 0, 0);
        }
        #pragma unroll
        for (int i = 0; i < 8; ++i) {
            const int g = i * 256 + t;
            __builtin_amdgcn_global_load_lds(
                (const void*)(wb + (size_t)kt * 32768 + g * 16),
                (void*)(lds_b + g * 16), 16, 0, 0);
        }
        __syncthreads();
        #pragma unroll
        for (int kk = 0; kk < 4; ++kk) {
            const int xo = (kk * 64 + q * 16);
            bf16x8 a = *(const bf16x8*)(lds_a + (r0 + p) * 256 + (xo ^ ps));
            #pragma unroll
            for (int n = 0; n < 8; ++n) {
                bf16x8 b = *(const bf16x8*)(lds_b + (n * 16 + p) * 256 + (xo ^ ps));
                acc[n] = __builtin_amdgcn_mfma_f32_16x16x32_bf16(a, b, acc[n], 0, 0, 0);
            }
        }
        __syncthreads();
    }
    #pragma unroll
    for (int n = 0; n < 8; ++n) {
        #pragma unroll
        for (int j = 0; j < 4; ++j) {
            const float v = acc[n][j];
            out[(size_t)(m0 + r0 + q * 4 + j) * EDIM + n * 16 + p] = v > 0.f ? v : 0.f;
        }
    }
}

extern "C" void kernel_launch(void* const* d_in, const int* in_sizes, int n_in,
                              void* d_out, int out_size, void* d_ws, size_t ws_size,
                              hipStream_t stream) {
    const int*   nodes  = (const int*)d_in[0];
    const int*   neigh  = (const int*)d_in[1];
    const float* feat   = (const float*)d_in[2];
    const float* weight = (const float*)d_in[3];
    float*       out    = (float*)d_out;

    if (ws_size >= NEW_WS) {
        char* Sb  = (char*)d_ws;
        char* Pb  = (char*)d_ws + SP_BYTES;
        char* wbt = (char*)d_ws + 2 * SP_BYTES;
        conv_w2<<<32, 256, 0, stream>>>(weight, wbt);
        proj<<<(NNODES + 63) / 64, 256, 0, stream>>>(feat, wbt, Sb, Pb);
        gather2<<<BATCH / 4, 256, 0, stream>>>(nodes, neigh, Sb, Pb, out);
    } else {
        char* cat = (char*)d_ws;
        char* wb  = (char*)d_ws + CAT_BYTES;
        conv_w<<<32, 256, 0, stream>>>(weight, wb);
        gather_agg<<<BATCH / 4, 256, 0, stream>>>(nodes, neigh, feat, cat);
        gemm_out<<<BATCH / 64, 256, 0, stream>>>(cat, wb, out);
    }
}